// Round 1
// 1467.085 us; speedup vs baseline: 1.0885x; 1.0885x over previous
//
#include <hip/hip_runtime.h>
#include <math.h>

typedef _Float16 h16;
typedef _Float16 half8 __attribute__((ext_vector_type(8)));
typedef _Float16 half4 __attribute__((ext_vector_type(4)));
typedef float floatx4 __attribute__((ext_vector_type(4)));

#define MFMA16(a, b, c) __builtin_amdgcn_mfma_f32_16x16x32_f16(a, b, c, 0, 0, 0)

__device__ __forceinline__ void gload16(const void* g, void* l) {
    __builtin_amdgcn_global_load_lds((const __attribute__((address_space(1))) unsigned int*)g,
                                     (__attribute__((address_space(3))) unsigned int*)l, 16, 0, 0);
}

// ---------------- sigma: one power iteration ----------------
__global__ void sigma_s1(const float* __restrict__ w0, const float* __restrict__ w1,
                         const float* __restrict__ w2, const float* __restrict__ w3,
                         const float* __restrict__ u0, const float* __restrict__ u1,
                         const float* __restrict__ u2, const float* __restrict__ u3,
                         float* __restrict__ tvec, float* __restrict__ acc) {
    int m = blockIdx.y;
    const float* w = (m == 0) ? w0 : (m == 1) ? w1 : (m == 2) ? w2 : w3;
    const float* u = (m == 0) ? u0 : (m == 1) ? u1 : (m == 2) ? u2 : u3;
    int wid = threadIdx.x >> 6, lane = threadIdx.x & 63;
    int row = blockIdx.x * 4 + wid;
    const float* wr = w + row * 1024;
    float s = 0.f;
    for (int k = 0; k < 16; k++) { int j = lane + 64 * k; s += u[j] * wr[j]; }
    for (int off = 32; off; off >>= 1) s += __shfl_xor(s, off, 64);
    if (lane == 0) { tvec[m * 1024 + row] = s; atomicAdd(acc + m * 2, s * s); }
}

__global__ void sigma_s2(const float* __restrict__ w0, const float* __restrict__ w1,
                         const float* __restrict__ w2, const float* __restrict__ w3,
                         const float* __restrict__ tvec, float* __restrict__ acc) {
    int m = blockIdx.y;
    const float* w = (m == 0) ? w0 : (m == 1) ? w1 : (m == 2) ? w2 : w3;
    const float* t = tvec + m * 1024;
    int j = blockIdx.x * 256 + threadIdx.x;
    float z = 0.f;
    for (int i = 0; i < 1024; i++) z += t[i] * w[i * 1024 + j];
    z = z * z;
    for (int off = 32; off; off >>= 1) z += __shfl_xor(z, off, 64);
    __shared__ float red[4];
    int wid = threadIdx.x >> 6, lane = threadIdx.x & 63;
    if (lane == 0) red[wid] = z;
    __syncthreads();
    if (threadIdx.x == 0) atomicAdd(acc + m * 2 + 1, red[0] + red[1] + red[2] + red[3]);
}

__global__ void sigma_s3(const float* __restrict__ acc, float* __restrict__ inv_sigma) {
    int m = threadIdx.x;
    if (m < 4) inv_sigma[m] = sqrtf(acc[m * 2] / acc[m * 2 + 1]);
}

// -------- W prep: scale by 1/sigma, transpose to [out][in], split f16 hi/lo --------
__global__ void prep_w(const float* __restrict__ w, const float* __restrict__ inv_sigma,
                       int midx, h16* __restrict__ whT, h16* __restrict__ wlT) {
    __shared__ float tile[32][33];
    float is = inv_sigma[midx];
    int i0 = blockIdx.x * 32, j0 = blockIdx.y * 32;
    int tx = threadIdx.x, ty = threadIdx.y;
    for (int r = 0; r < 32; r += 8)
        tile[r + ty][tx] = w[(i0 + r + ty) * 1024 + j0 + tx] * is;
    __syncthreads();
    for (int r = 0; r < 32; r += 8) {
        int j = j0 + r + ty, i = i0 + tx;
        float v = tile[tx][r + ty];
        h16 h = (h16)v;
        whT[j * 1024 + i] = h;
        wlT[j * 1024 + i] = (h16)(v - (float)h);
    }
}

// -------- x prep: split f16 hi/lo --------
__global__ void prep_x(const float4* __restrict__ x4, half4* __restrict__ xh,
                       half4* __restrict__ xl) {
    int i = blockIdx.x * 256 + threadIdx.x;
    float4 v = x4[i];
    float a[4] = {v.x, v.y, v.z, v.w};
    half4 h, l;
    for (int k = 0; k < 4; k++) {
        h16 hh = (h16)a[k];
        h[k] = hh;
        l[k] = (h16)(a[k] - (float)hh);
    }
    xh[i] = h;
    xl[i] = l;
}

// -------- projection GEMM: C[8192,1024] = A[8192,1024] @ B + bias, head-split output --------
// global_load_lds staging (m97 structure): linear LDS [128][32] h16, BK=32, 2-barrier loop.
template <int SPLIT>
__global__ __launch_bounds__(256, 2) void gemm_proj(
    const h16* __restrict__ Ah_g, const h16* __restrict__ Al_g,
    const h16* __restrict__ Bh_g, const h16* __restrict__ Bl_g,
    const float* __restrict__ bias, h16* __restrict__ outh, h16* __restrict__ outl) {
    __shared__ h16 As[2][128 * 32];
    __shared__ h16 Bs[2][128 * 32];
    int tid = threadIdx.x;
    int m0 = blockIdx.y * 128, n0 = blockIdx.x * 128;
    int wid = tid >> 6, lane = tid & 63;
    int wm = (wid >> 1) * 64, wn = (wid & 1) * 64;
    int lrow = lane & 15, quad = lane >> 4;
    int srow = lane >> 2;        // 16 rows per wave-load
    int scol = (lane & 3) * 8;   // 8 h16 = 16B per lane
    floatx4 acc[4][4] = {};
    for (int kt = 0; kt < 1024; kt += 32) {
        for (int j = 0; j < 2; j++) {
            int rb = j * 64 + wid * 16;
            int r = rb + srow;
            gload16(&Ah_g[(size_t)(m0 + r) * 1024 + kt + scol], &As[0][rb * 32]);
            gload16(&Bh_g[(size_t)(n0 + r) * 1024 + kt + scol], &Bs[0][rb * 32]);
            if (SPLIT) {
                gload16(&Al_g[(size_t)(m0 + r) * 1024 + kt + scol], &As[1][rb * 32]);
                gload16(&Bl_g[(size_t)(n0 + r) * 1024 + kt + scol], &Bs[1][rb * 32]);
            }
        }
        __syncthreads();
        half8 a_h[4], a_l[4], b_h[4], b_l[4];
        for (int f = 0; f < 4; f++) {
            a_h[f] = *(const half8*)&As[0][(wm + f * 16 + lrow) * 32 + quad * 8];
            b_h[f] = *(const half8*)&Bs[0][(wn + f * 16 + lrow) * 32 + quad * 8];
            if (SPLIT) {
                a_l[f] = *(const half8*)&As[1][(wm + f * 16 + lrow) * 32 + quad * 8];
                b_l[f] = *(const half8*)&Bs[1][(wn + f * 16 + lrow) * 32 + quad * 8];
            }
        }
        for (int mf = 0; mf < 4; mf++)
            for (int nf = 0; nf < 4; nf++) {
                acc[mf][nf] = MFMA16(a_h[mf], b_h[nf], acc[mf][nf]);
                if (SPLIT) {
                    acc[mf][nf] = MFMA16(a_h[mf], b_l[nf], acc[mf][nf]);
                    acc[mf][nf] = MFMA16(a_l[mf], b_h[nf], acc[mf][nf]);
                }
            }
        __syncthreads();
    }
    for (int nf = 0; nf < 4; nf++) {
        int n = n0 + wn + nf * 16 + lrow;
        float b = bias[n];
        int h = n >> 7, d = n & 127;
        for (int mf = 0; mf < 4; mf++)
            for (int r = 0; r < 4; r++) {
                int mg = m0 + wm + mf * 16 + quad * 4 + r;
                int bb = mg >> 11, s = mg & 2047;
                int idx = ((bb * 8 + h) * 2048 + s) * 128 + d;
                float v = acc[mf][nf][r] + b;
                h16 hh = (h16)v;
                outh[idx] = hh;
                if (SPLIT) outl[idx] = (h16)(v - (float)hh);
            }
    }
}

// -------- v transpose: [bh][t][d] -> [bh][d][t] (f16) --------
__global__ void transpose_v(const h16* __restrict__ vh, h16* __restrict__ vT) {
    __shared__ h16 tile[32][33];
    int bh = blockIdx.z;
    int t0 = blockIdx.x * 32, d0 = blockIdx.y * 32;
    int tx = threadIdx.x, ty = threadIdx.y;
    const h16* src = vh + bh * 2048 * 128;
    h16* dst = vT + bh * 128 * 2048;
    for (int r = 0; r < 32; r += 8) tile[r + ty][tx] = src[(t0 + r + ty) * 128 + d0 + tx];
    __syncthreads();
    for (int r = 0; r < 32; r += 8) dst[(d0 + r + ty) * 2048 + t0 + tx] = tile[tx][r + ty];
}

// -------- logits GEMM + fused row-stat partials --------
// attn[bh][s][t] = sum_d q[s][d] k[t][d] (split-3, fp32 out); per-(row, 64-col tile)
// max and sum(exp(l - max)) partials written for the combine pass.
__global__ __launch_bounds__(256, 2) void gemm_logits(
    const h16* __restrict__ qh, const h16* __restrict__ ql,
    const h16* __restrict__ kh, const h16* __restrict__ kl, float* __restrict__ attn,
    float* __restrict__ pmax, float* __restrict__ psum) {
    __shared__ h16 As[2][128 * 32];
    __shared__ h16 Bs[2][128 * 32];
    int tid = threadIdx.x;
    int bh = blockIdx.z;
    int s0 = blockIdx.y * 128, t0 = blockIdx.x * 128;
    const h16* Ah_g = qh + bh * 2048 * 128;
    const h16* Al_g = ql + bh * 2048 * 128;
    const h16* Bh_g = kh + bh * 2048 * 128;
    const h16* Bl_g = kl + bh * 2048 * 128;
    int wid = tid >> 6, lane = tid & 63;
    int wm = (wid >> 1) * 64, wn = (wid & 1) * 64;
    int lrow = lane & 15, quad = lane >> 4;
    int srow = lane >> 2;
    int scol = (lane & 3) * 8;
    floatx4 acc[4][4] = {};
    for (int kt = 0; kt < 128; kt += 32) {
        for (int j = 0; j < 2; j++) {
            int rb = j * 64 + wid * 16;
            int r = rb + srow;
            gload16(&Ah_g[(size_t)(s0 + r) * 128 + kt + scol], &As[0][rb * 32]);
            gload16(&Al_g[(size_t)(s0 + r) * 128 + kt + scol], &As[1][rb * 32]);
            gload16(&Bh_g[(size_t)(t0 + r) * 128 + kt + scol], &Bs[0][rb * 32]);
            gload16(&Bl_g[(size_t)(t0 + r) * 128 + kt + scol], &Bs[1][rb * 32]);
        }
        __syncthreads();
        half8 a_h[4], a_l[4], b_h[4], b_l[4];
        for (int f = 0; f < 4; f++) {
            a_h[f] = *(const half8*)&As[0][(wm + f * 16 + lrow) * 32 + quad * 8];
            a_l[f] = *(const half8*)&As[1][(wm + f * 16 + lrow) * 32 + quad * 8];
            b_h[f] = *(const half8*)&Bs[0][(wn + f * 16 + lrow) * 32 + quad * 8];
            b_l[f] = *(const half8*)&Bs[1][(wn + f * 16 + lrow) * 32 + quad * 8];
        }
        for (int mf = 0; mf < 4; mf++)
            for (int nf = 0; nf < 4; nf++) {
                acc[mf][nf] = MFMA16(a_h[mf], b_h[nf], acc[mf][nf]);
                acc[mf][nf] = MFMA16(a_h[mf], b_l[nf], acc[mf][nf]);
                acc[mf][nf] = MFMA16(a_l[mf], b_h[nf], acc[mf][nf]);
            }
        __syncthreads();
    }
    // write logits
    for (int nf = 0; nf < 4; nf++) {
        int t = t0 + wn + nf * 16 + lrow;
        for (int mf = 0; mf < 4; mf++)
            for (int r = 0; r < 4; r++) {
                int s = s0 + wm + mf * 16 + quad * 4 + r;
                attn[((size_t)bh * 2048 + s) * 2048 + t] = acc[mf][nf][r];
            }
    }
    // fused stats: per row, max/sumexp over this wave's 64 columns
    int tile = blockIdx.x * 2 + (wid & 1);
    for (int mf = 0; mf < 4; mf++)
        for (int r = 0; r < 4; r++) {
            float mx = fmaxf(fmaxf(acc[mf][0][r], acc[mf][1][r]),
                             fmaxf(acc[mf][2][r], acc[mf][3][r]));
            for (int off = 8; off; off >>= 1) mx = fmaxf(mx, __shfl_xor(mx, off, 64));
            float z = __expf(acc[mf][0][r] - mx) + __expf(acc[mf][1][r] - mx) +
                      __expf(acc[mf][2][r] - mx) + __expf(acc[mf][3][r] - mx);
            for (int off = 8; off; off >>= 1) z += __shfl_xor(z, off, 64);
            if (lrow == 0) {
                int s = s0 + wm + mf * 16 + quad * 4 + r;
                pmax[((size_t)bh * 2048 + s) * 32 + tile] = mx;
                psum[((size_t)bh * 2048 + s) * 32 + tile] = z;
            }
        }
}

// -------- combine per-tile stats into final row max / denom --------
__global__ void combine_stats(const float* __restrict__ pmax, const float* __restrict__ psum,
                              float* __restrict__ m_arr, float* __restrict__ z_arr) {
    int r = blockIdx.x * 256 + threadIdx.x;  // 65536 rows
    const float* pm = pmax + (size_t)r * 32;
    const float* ps = psum + (size_t)r * 32;
    float m = -1e30f;
    for (int i = 0; i < 32; i++) m = fmaxf(m, pm[i]);
    float z = 0.f;
    for (int i = 0; i < 32; i++) z += ps[i] * __expf(pm[i] - m);
    m_arr[r] = m;
    z_arr[r] = z;
}

// -------- PV pass: p = softmax (written back fp32), ctx = p @ v (f16 MFMA) --------
__global__ __launch_bounds__(256, 2) void gemm_pv(
    float* __restrict__ attn, const h16* __restrict__ vT, const float* __restrict__ m_arr,
    const float* __restrict__ z_arr, h16* __restrict__ ctx) {
    __shared__ h16 Ps[128 * 72];
    __shared__ h16 Vs[128 * 72];
    __shared__ float ms[128], izs[128];
    int tid = threadIdx.x;
    int bh = blockIdx.y, s0 = blockIdx.x * 128;
    if (tid < 128) ms[tid] = m_arr[bh * 2048 + s0 + tid];
    else izs[tid - 128] = 1.f / z_arr[bh * 2048 + s0 + tid - 128];
    __syncthreads();
    int wid = tid >> 6, lane = tid & 63;
    int wm = (wid >> 1) * 64, wn = (wid & 1) * 64;
    int lrow = lane & 15, quad = lane >> 4;
    float* attn_b = attn + ((size_t)bh * 2048 + s0) * 2048;
    const h16* vT_b = vT + bh * 128 * 2048;
    floatx4 acc[4][4] = {};
    for (int t0 = 0; t0 < 2048; t0 += 64) {
        for (int i = 0; i < 8; i++) {
            int c = tid + 256 * i;
            int row = c >> 4, c4 = c & 15;
            float4* p = (float4*)&attn_b[(size_t)row * 2048 + t0 + c4 * 4];
            float4 l = *p;
            float mm = ms[row], iz = izs[row];
            float4 e;
            e.x = __expf(l.x - mm) * iz;
            e.y = __expf(l.y - mm) * iz;
            e.z = __expf(l.z - mm) * iz;
            e.w = __expf(l.w - mm) * iz;
            *p = e;
            half4 ph;
            ph[0] = (h16)e.x; ph[1] = (h16)e.y; ph[2] = (h16)e.z; ph[3] = (h16)e.w;
            *(half4*)&Ps[row * 72 + c4 * 4] = ph;
        }
        for (int i = 0; i < 4; i++) {
            int c = tid + 256 * i;
            int row = c >> 3, c8 = (c & 7) * 8;
            *(half8*)&Vs[row * 72 + c8] = *(const half8*)&vT_b[row * 2048 + t0 + c8];
        }
        __syncthreads();
        for (int ks = 0; ks < 2; ks++) {
            half8 a[4], b[4];
            for (int f = 0; f < 4; f++) {
                a[f] = *(const half8*)&Ps[(wm + f * 16 + lrow) * 72 + ks * 32 + quad * 8];
                b[f] = *(const half8*)&Vs[(wn + f * 16 + lrow) * 72 + ks * 32 + quad * 8];
            }
            for (int mf = 0; mf < 4; mf++)
                for (int nf = 0; nf < 4; nf++)
                    acc[mf][nf] = MFMA16(a[mf], b[nf], acc[mf][nf]);
        }
        __syncthreads();
    }
    int b = bh >> 3, h = bh & 7;
    for (int nf = 0; nf < 4; nf++) {
        int d = wn + nf * 16 + lrow;
        for (int mf = 0; mf < 4; mf++)
            for (int r = 0; r < 4; r++) {
                int s = s0 + wm + mf * 16 + quad * 4 + r;
                ctx[(b * 2048 + s) * 1024 + h * 128 + d] = (h16)acc[mf][nf][r];
            }
    }
}

// -------- output GEMM: out = x + (ctx @ WoT + bo) * gamma --------
__global__ __launch_bounds__(256, 2) void gemm_out(
    const h16* __restrict__ Ah_g, const h16* __restrict__ Bh_g, const float* __restrict__ bo,
    const float* __restrict__ x, const float* __restrict__ gamma_p, float* __restrict__ out) {
    __shared__ h16 As[128 * 32];
    __shared__ h16 Bs[128 * 32];
    int tid = threadIdx.x;
    int m0 = blockIdx.y * 128, n0 = blockIdx.x * 128;
    int wid = tid >> 6, lane = tid & 63;
    int wm = (wid >> 1) * 64, wn = (wid & 1) * 64;
    int lrow = lane & 15, quad = lane >> 4;
    int srow = lane >> 2;
    int scol = (lane & 3) * 8;
    floatx4 acc[4][4] = {};
    for (int kt = 0; kt < 1024; kt += 32) {
        for (int j = 0; j < 2; j++) {
            int rb = j * 64 + wid * 16;
            int r = rb + srow;
            gload16(&Ah_g[(size_t)(m0 + r) * 1024 + kt + scol], &As[rb * 32]);
            gload16(&Bh_g[(size_t)(n0 + r) * 1024 + kt + scol], &Bs[rb * 32]);
        }
        __syncthreads();
        half8 a[4], b[4];
        for (int f = 0; f < 4; f++) {
            a[f] = *(const half8*)&As[(wm + f * 16 + lrow) * 32 + quad * 8];
            b[f] = *(const half8*)&Bs[(wn + f * 16 + lrow) * 32 + quad * 8];
        }
        for (int mf = 0; mf < 4; mf++)
            for (int nf = 0; nf < 4; nf++)
                acc[mf][nf] = MFMA16(a[mf], b[nf], acc[mf][nf]);
        __syncthreads();
    }
    float g = *gamma_p;
    for (int nf = 0; nf < 4; nf++) {
        int n = n0 + wn + nf * 16 + lrow;
        float bb = bo[n];
        for (int mf = 0; mf < 4; mf++)
            for (int r = 0; r < 4; r++) {
                int mg = m0 + wm + mf * 16 + quad * 4 + r;
                out[mg * 1024 + n] = x[mg * 1024 + n] + (acc[mf][nf][r] + bb) * g;
            }
    }
}

extern "C" void kernel_launch(void* const* d_in, const int* in_sizes, int n_in,
                              void* d_out, int out_size, void* d_ws, size_t ws_size,
                              hipStream_t stream) {
    const float* x = (const float*)d_in[0];
    const float* wq = (const float*)d_in[1];
    const float* bq = (const float*)d_in[2];
    const float* uq = (const float*)d_in[3];
    const float* wk = (const float*)d_in[4];
    const float* bk = (const float*)d_in[5];
    const float* uk = (const float*)d_in[6];
    const float* wv = (const float*)d_in[7];
    const float* bv = (const float*)d_in[8];
    const float* uv = (const float*)d_in[9];
    const float* wo = (const float*)d_in[10];
    const float* bo = (const float*)d_in[11];
    const float* uo = (const float*)d_in[12];
    const float* gamma = (const float*)d_in[13];
    float* out_f = (float*)d_out;
    float* attn = out_f + 8388608;  // [4,8,2048,2048]

    char* ws = (char*)d_ws;
    size_t o = 0;
    auto alloc = [&](size_t b) { size_t r = o; o += (b + 255) & ~(size_t)255; return r; };
    const size_t SZ_X = (size_t)8192 * 1024 * 2;   // f16 [8192][1024]
    const size_t SZ_W = (size_t)1024 * 1024 * 2;   // f16 [1024][1024]
    const size_t SZ_Q = (size_t)32 * 2048 * 128 * 2;  // f16 [bh][s][d]
    h16* xh = (h16*)(ws + alloc(SZ_X));
    h16* xl = (h16*)(ws + alloc(SZ_X));
    h16* wqhT = (h16*)(ws + alloc(SZ_W));
    h16* wqlT = (h16*)(ws + alloc(SZ_W));
    h16* wkhT = (h16*)(ws + alloc(SZ_W));
    h16* wklT = (h16*)(ws + alloc(SZ_W));
    h16* wvhT = (h16*)(ws + alloc(SZ_W));
    h16* wvlT = (h16*)(ws + alloc(SZ_W));
    h16* wohT = (h16*)(ws + alloc(SZ_W));
    h16* wolT = (h16*)(ws + alloc(SZ_W));
    h16* qh = (h16*)(ws + alloc(SZ_Q));
    h16* ql = (h16*)(ws + alloc(SZ_Q));
    h16* kh = (h16*)(ws + alloc(SZ_Q));
    h16* kl = (h16*)(ws + alloc(SZ_Q));
    h16* vh = (h16*)(ws + alloc(SZ_Q));
    h16* vT = (h16*)(ws + alloc(SZ_Q));
    h16* ctx = (h16*)(ws + alloc(SZ_Q));
    float* tvec = (float*)(ws + alloc(4096 * 4));
    float* sacc = (float*)(ws + alloc(8 * 4));
    float* isig = (float*)(ws + alloc(4 * 4));
    float* m_arr = (float*)(ws + alloc(65536 * 4));
    float* z_arr = (float*)(ws + alloc(65536 * 4));
    // stat partials overlay ctx (ctx is only written by gemm_pv, after combine_stats
    // has consumed pmax/psum; stream order serializes) : 2 x 8 MB fits in 16.78 MB
    float* pmax = (float*)ctx;
    float* psum = pmax + (size_t)65536 * 32;

    (void)hipMemsetAsync(sacc, 0, 8 * 4, stream);
    sigma_s1<<<dim3(256, 4), 256, 0, stream>>>(wq, wk, wv, wo, uq, uk, uv, uo, tvec, sacc);
    sigma_s2<<<dim3(4, 4), 256, 0, stream>>>(wq, wk, wv, wo, tvec, sacc);
    sigma_s3<<<1, 64, 0, stream>>>(sacc, isig);

    prep_w<<<dim3(32, 32), dim3(32, 8), 0, stream>>>(wq, isig, 0, wqhT, wqlT);
    prep_w<<<dim3(32, 32), dim3(32, 8), 0, stream>>>(wk, isig, 1, wkhT, wklT);
    prep_w<<<dim3(32, 32), dim3(32, 8), 0, stream>>>(wv, isig, 2, wvhT, wvlT);
    prep_w<<<dim3(32, 32), dim3(32, 8), 0, stream>>>(wo, isig, 3, wohT, wolT);
    prep_x<<<8192, 256, 0, stream>>>((const float4*)x, (half4*)xh, (half4*)xl);

    gemm_proj<1><<<dim3(8, 64), 256, 0, stream>>>(xh, xl, wqhT, wqlT, bq, qh, ql);
    gemm_proj<1><<<dim3(8, 64), 256, 0, stream>>>(xh, xl, wkhT, wklT, bk, kh, kl);
    gemm_proj<0><<<dim3(8, 64), 256, 0, stream>>>(xh, xl, wvhT, wvlT, bv, vh, nullptr);
    transpose_v<<<dim3(64, 4, 32), dim3(32, 8), 0, stream>>>(vh, vT);

    gemm_logits<<<dim3(16, 16, 32), 256, 0, stream>>>(qh, ql, kh, kl, attn, pmax, psum);
    combine_stats<<<256, 256, 0, stream>>>(pmax, psum, m_arr, z_arr);
    gemm_pv<<<dim3(16, 32), 256, 0, stream>>>(attn, vT, m_arr, z_arr, ctx);
    gemm_out<<<dim3(8, 64), 256, 0, stream>>>(ctx, wohT, bo, x, gamma, out_f);

    (void)in_sizes; (void)n_in; (void)out_size; (void)ws_size;
}

// Round 2
// 1385.717 us; speedup vs baseline: 1.1524x; 1.0587x over previous
//
#include <hip/hip_runtime.h>
#include <math.h>

typedef _Float16 h16;
typedef _Float16 half8 __attribute__((ext_vector_type(8)));
typedef _Float16 half4 __attribute__((ext_vector_type(4)));
typedef float floatx4 __attribute__((ext_vector_type(4)));

#define MFMA16(a, b, c) __builtin_amdgcn_mfma_f32_16x16x32_f16(a, b, c, 0, 0, 0)

__device__ __forceinline__ void gload16(const void* g, void* l) {
    __builtin_amdgcn_global_load_lds((const __attribute__((address_space(1))) unsigned int*)g,
                                     (__attribute__((address_space(3))) unsigned int*)l, 16, 0, 0);
}

// ---------------- sigma: one power iteration ----------------
__global__ void sigma_s1(const float* __restrict__ w0, const float* __restrict__ w1,
                         const float* __restrict__ w2, const float* __restrict__ w3,
                         const float* __restrict__ u0, const float* __restrict__ u1,
                         const float* __restrict__ u2, const float* __restrict__ u3,
                         float* __restrict__ tvec, float* __restrict__ acc) {
    int m = blockIdx.y;
    const float* w = (m == 0) ? w0 : (m == 1) ? w1 : (m == 2) ? w2 : w3;
    const float* u = (m == 0) ? u0 : (m == 1) ? u1 : (m == 2) ? u2 : u3;
    int wid = threadIdx.x >> 6, lane = threadIdx.x & 63;
    int row = blockIdx.x * 4 + wid;
    const float* wr = w + row * 1024;
    float s = 0.f;
    for (int k = 0; k < 16; k++) { int j = lane + 64 * k; s += u[j] * wr[j]; }
    for (int off = 32; off; off >>= 1) s += __shfl_xor(s, off, 64);
    if (lane == 0) { tvec[m * 1024 + row] = s; atomicAdd(acc + m * 2, s * s); }
}

__global__ void sigma_s2(const float* __restrict__ w0, const float* __restrict__ w1,
                         const float* __restrict__ w2, const float* __restrict__ w3,
                         const float* __restrict__ tvec, float* __restrict__ acc) {
    int m = blockIdx.y;
    const float* w = (m == 0) ? w0 : (m == 1) ? w1 : (m == 2) ? w2 : w3;
    const float* t = tvec + m * 1024;
    int j = blockIdx.x * 256 + threadIdx.x;
    float z = 0.f;
    for (int i = 0; i < 1024; i++) z += t[i] * w[i * 1024 + j];
    z = z * z;
    for (int off = 32; off; off >>= 1) z += __shfl_xor(z, off, 64);
    __shared__ float red[4];
    int wid = threadIdx.x >> 6, lane = threadIdx.x & 63;
    if (lane == 0) red[wid] = z;
    __syncthreads();
    if (threadIdx.x == 0) atomicAdd(acc + m * 2 + 1, red[0] + red[1] + red[2] + red[3]);
}

__global__ void sigma_s3(const float* __restrict__ acc, float* __restrict__ inv_sigma) {
    int m = threadIdx.x;
    if (m < 4) inv_sigma[m] = sqrtf(acc[m * 2] / acc[m * 2 + 1]);
}

// -------- W prep: scale by 1/sigma, transpose to [out][in], split f16 hi/lo --------
__global__ void prep_w(const float* __restrict__ w, const float* __restrict__ inv_sigma,
                       int midx, h16* __restrict__ whT, h16* __restrict__ wlT) {
    __shared__ float tile[32][33];
    float is = inv_sigma[midx];
    int i0 = blockIdx.x * 32, j0 = blockIdx.y * 32;
    int tx = threadIdx.x, ty = threadIdx.y;
    for (int r = 0; r < 32; r += 8)
        tile[r + ty][tx] = w[(i0 + r + ty) * 1024 + j0 + tx] * is;
    __syncthreads();
    for (int r = 0; r < 32; r += 8) {
        int j = j0 + r + ty, i = i0 + tx;
        float v = tile[tx][r + ty];
        h16 h = (h16)v;
        whT[j * 1024 + i] = h;
        wlT[j * 1024 + i] = (h16)(v - (float)h);
    }
}

// -------- x prep: split f16 hi/lo --------
__global__ void prep_x(const float4* __restrict__ x4, half4* __restrict__ xh,
                       half4* __restrict__ xl) {
    int i = blockIdx.x * 256 + threadIdx.x;
    float4 v = x4[i];
    float a[4] = {v.x, v.y, v.z, v.w};
    half4 h, l;
    for (int k = 0; k < 4; k++) {
        h16 hh = (h16)a[k];
        h[k] = hh;
        l[k] = (h16)(a[k] - (float)hh);
    }
    xh[i] = h;
    xl[i] = l;
}

// -------- projection GEMM: C[8192,1024] = A[8192,1024] @ B + bias, head-split output --------
// global_load_lds staging (m97 structure): linear LDS [128][32] h16, BK=32, 2-barrier loop.
template <int SPLIT>
__global__ __launch_bounds__(256, 2) void gemm_proj(
    const h16* __restrict__ Ah_g, const h16* __restrict__ Al_g,
    const h16* __restrict__ Bh_g, const h16* __restrict__ Bl_g,
    const float* __restrict__ bias, h16* __restrict__ outh, h16* __restrict__ outl) {
    __shared__ h16 As[2][128 * 32];
    __shared__ h16 Bs[2][128 * 32];
    int tid = threadIdx.x;
    int m0 = blockIdx.y * 128, n0 = blockIdx.x * 128;
    int wid = tid >> 6, lane = tid & 63;
    int wm = (wid >> 1) * 64, wn = (wid & 1) * 64;
    int lrow = lane & 15, quad = lane >> 4;
    int srow = lane >> 2;        // 16 rows per wave-load
    int scol = (lane & 3) * 8;   // 8 h16 = 16B per lane
    floatx4 acc[4][4] = {};
    for (int kt = 0; kt < 1024; kt += 32) {
        for (int j = 0; j < 2; j++) {
            int rb = j * 64 + wid * 16;
            int r = rb + srow;
            gload16(&Ah_g[(size_t)(m0 + r) * 1024 + kt + scol], &As[0][rb * 32]);
            gload16(&Bh_g[(size_t)(n0 + r) * 1024 + kt + scol], &Bs[0][rb * 32]);
            if (SPLIT) {
                gload16(&Al_g[(size_t)(m0 + r) * 1024 + kt + scol], &As[1][rb * 32]);
                gload16(&Bl_g[(size_t)(n0 + r) * 1024 + kt + scol], &Bs[1][rb * 32]);
            }
        }
        __syncthreads();
        half8 a_h[4], a_l[4], b_h[4], b_l[4];
        for (int f = 0; f < 4; f++) {
            a_h[f] = *(const half8*)&As[0][(wm + f * 16 + lrow) * 32 + quad * 8];
            b_h[f] = *(const half8*)&Bs[0][(wn + f * 16 + lrow) * 32 + quad * 8];
            if (SPLIT) {
                a_l[f] = *(const half8*)&As[1][(wm + f * 16 + lrow) * 32 + quad * 8];
                b_l[f] = *(const half8*)&Bs[1][(wn + f * 16 + lrow) * 32 + quad * 8];
            }
        }
        for (int mf = 0; mf < 4; mf++)
            for (int nf = 0; nf < 4; nf++) {
                acc[mf][nf] = MFMA16(a_h[mf], b_h[nf], acc[mf][nf]);
                if (SPLIT) {
                    acc[mf][nf] = MFMA16(a_h[mf], b_l[nf], acc[mf][nf]);
                    acc[mf][nf] = MFMA16(a_l[mf], b_h[nf], acc[mf][nf]);
                }
            }
        __syncthreads();
    }
    for (int nf = 0; nf < 4; nf++) {
        int n = n0 + wn + nf * 16 + lrow;
        float b = bias[n];
        int h = n >> 7, d = n & 127;
        for (int mf = 0; mf < 4; mf++)
            for (int r = 0; r < 4; r++) {
                int mg = m0 + wm + mf * 16 + quad * 4 + r;
                int bb = mg >> 11, s = mg & 2047;
                int idx = ((bb * 8 + h) * 2048 + s) * 128 + d;
                float v = acc[mf][nf][r] + b;
                h16 hh = (h16)v;
                outh[idx] = hh;
                if (SPLIT) outl[idx] = (h16)(v - (float)hh);
            }
    }
}

// -------- v transpose: [bh][t][d] -> [bh][d][t] (f16) --------
__global__ void transpose_v(const h16* __restrict__ vh, h16* __restrict__ vT) {
    __shared__ h16 tile[32][33];
    int bh = blockIdx.z;
    int t0 = blockIdx.x * 32, d0 = blockIdx.y * 32;
    int tx = threadIdx.x, ty = threadIdx.y;
    const h16* src = vh + bh * 2048 * 128;
    h16* dst = vT + bh * 128 * 2048;
    for (int r = 0; r < 32; r += 8) tile[r + ty][tx] = src[(t0 + r + ty) * 128 + d0 + tx];
    __syncthreads();
    for (int r = 0; r < 32; r += 8) dst[(d0 + r + ty) * 2048 + t0 + tx] = tile[tx][r + ty];
}

// -------- logits GEMM + fused row-stat partials --------
__global__ __launch_bounds__(256, 2) void gemm_logits(
    const h16* __restrict__ qh, const h16* __restrict__ ql,
    const h16* __restrict__ kh, const h16* __restrict__ kl, float* __restrict__ attn,
    float* __restrict__ pmax, float* __restrict__ psum) {
    __shared__ h16 As[2][128 * 32];
    __shared__ h16 Bs[2][128 * 32];
    int tid = threadIdx.x;
    int bh = blockIdx.z;
    int s0 = blockIdx.y * 128, t0 = blockIdx.x * 128;
    const h16* Ah_g = qh + bh * 2048 * 128;
    const h16* Al_g = ql + bh * 2048 * 128;
    const h16* Bh_g = kh + bh * 2048 * 128;
    const h16* Bl_g = kl + bh * 2048 * 128;
    int wid = tid >> 6, lane = tid & 63;
    int wm = (wid >> 1) * 64, wn = (wid & 1) * 64;
    int lrow = lane & 15, quad = lane >> 4;
    int srow = lane >> 2;
    int scol = (lane & 3) * 8;
    floatx4 acc[4][4] = {};
    for (int kt = 0; kt < 128; kt += 32) {
        for (int j = 0; j < 2; j++) {
            int rb = j * 64 + wid * 16;
            int r = rb + srow;
            gload16(&Ah_g[(size_t)(s0 + r) * 128 + kt + scol], &As[0][rb * 32]);
            gload16(&Al_g[(size_t)(s0 + r) * 128 + kt + scol], &As[1][rb * 32]);
            gload16(&Bh_g[(size_t)(t0 + r) * 128 + kt + scol], &Bs[0][rb * 32]);
            gload16(&Bl_g[(size_t)(t0 + r) * 128 + kt + scol], &Bs[1][rb * 32]);
        }
        __syncthreads();
        half8 a_h[4], a_l[4], b_h[4], b_l[4];
        for (int f = 0; f < 4; f++) {
            a_h[f] = *(const half8*)&As[0][(wm + f * 16 + lrow) * 32 + quad * 8];
            a_l[f] = *(const half8*)&As[1][(wm + f * 16 + lrow) * 32 + quad * 8];
            b_h[f] = *(const half8*)&Bs[0][(wn + f * 16 + lrow) * 32 + quad * 8];
            b_l[f] = *(const half8*)&Bs[1][(wn + f * 16 + lrow) * 32 + quad * 8];
        }
        for (int mf = 0; mf < 4; mf++)
            for (int nf = 0; nf < 4; nf++) {
                acc[mf][nf] = MFMA16(a_h[mf], b_h[nf], acc[mf][nf]);
                acc[mf][nf] = MFMA16(a_h[mf], b_l[nf], acc[mf][nf]);
                acc[mf][nf] = MFMA16(a_l[mf], b_h[nf], acc[mf][nf]);
            }
        __syncthreads();
    }
    for (int nf = 0; nf < 4; nf++) {
        int t = t0 + wn + nf * 16 + lrow;
        for (int mf = 0; mf < 4; mf++)
            for (int r = 0; r < 4; r++) {
                int s = s0 + wm + mf * 16 + quad * 4 + r;
                attn[((size_t)bh * 2048 + s) * 2048 + t] = acc[mf][nf][r];
            }
    }
    int tile = blockIdx.x * 2 + (wid & 1);
    for (int mf = 0; mf < 4; mf++)
        for (int r = 0; r < 4; r++) {
            float mx = fmaxf(fmaxf(acc[mf][0][r], acc[mf][1][r]),
                             fmaxf(acc[mf][2][r], acc[mf][3][r]));
            for (int off = 8; off; off >>= 1) mx = fmaxf(mx, __shfl_xor(mx, off, 64));
            float z = __expf(acc[mf][0][r] - mx) + __expf(acc[mf][1][r] - mx) +
                      __expf(acc[mf][2][r] - mx) + __expf(acc[mf][3][r] - mx);
            for (int off = 8; off; off >>= 1) z += __shfl_xor(z, off, 64);
            if (lrow == 0) {
                int s = s0 + wm + mf * 16 + quad * 4 + r;
                pmax[((size_t)bh * 2048 + s) * 32 + tile] = mx;
                psum[((size_t)bh * 2048 + s) * 32 + tile] = z;
            }
        }
}

// -------- combine per-tile stats into final row max / denom --------
__global__ void combine_stats(const float* __restrict__ pmax, const float* __restrict__ psum,
                              float* __restrict__ m_arr, float* __restrict__ z_arr) {
    int r = blockIdx.x * 256 + threadIdx.x;  // 65536 rows
    const float* pm = pmax + (size_t)r * 32;
    const float* ps = psum + (size_t)r * 32;
    float m = -1e30f;
    for (int i = 0; i < 32; i++) m = fmaxf(m, pm[i]);
    float z = 0.f;
    for (int i = 0; i < 32; i++) z += ps[i] * __expf(pm[i] - m);
    m_arr[r] = m;
    z_arr[r] = z;
}

// -------- PV pass: p = softmax (written back fp32), ctx = p @ v (f16 MFMA) --------
// Latency-hiding version: register prefetch of next attn/V tile (T14), 3 blocks/CU,
// per-row m,1/z cached in registers.
__global__ __launch_bounds__(256, 3) void gemm_pv(
    float* __restrict__ attn, const h16* __restrict__ vT, const float* __restrict__ m_arr,
    const float* __restrict__ z_arr, h16* __restrict__ ctx) {
    __shared__ h16 Ps[128 * 72];
    __shared__ h16 Vs[128 * 72];
    __shared__ float ms[128], izs[128];
    int tid = threadIdx.x;
    int bh = blockIdx.y, s0 = blockIdx.x * 128;
    if (tid < 128) ms[tid] = m_arr[bh * 2048 + s0 + tid];
    else izs[tid - 128] = 1.f / z_arr[bh * 2048 + s0 + tid - 128];
    int wid = tid >> 6, lane = tid & 63;
    int wm = (wid >> 1) * 64, wn = (wid & 1) * 64;
    int lrow = lane & 15, quad = lane >> 4;
    float* attn_b = attn + ((size_t)bh * 2048 + s0) * 2048;
    const h16* vT_b = vT + bh * 128 * 2048;
    int prow = tid >> 4, pc4 = (tid & 15) * 4;   // P tile: 8 rows/thread (stride 16), 4 floats
    int vrow = tid >> 3, vc8 = (tid & 7) * 8;    // V tile: 4 rows/thread (stride 32), 8 h16
    __syncthreads();
    float mm[8], iz[8];
#pragma unroll
    for (int i = 0; i < 8; i++) { mm[i] = ms[prow + 16 * i]; iz[i] = izs[prow + 16 * i]; }
    // prefetch tile 0
    float4 preP[8];
    half8 preV[4];
#pragma unroll
    for (int i = 0; i < 8; i++)
        preP[i] = *(const float4*)&attn_b[(size_t)(prow + 16 * i) * 2048 + pc4];
#pragma unroll
    for (int i = 0; i < 4; i++)
        preV[i] = *(const half8*)&vT_b[(vrow + 32 * i) * 2048 + vc8];
    floatx4 acc[4][4] = {};
    for (int t0 = 0; t0 < 2048; t0 += 64) {
        // phase A: consume prefetched tile (exp + writeback + LDS), then issue next tile's loads
#pragma unroll
        for (int i = 0; i < 8; i++) {
            float4 l = preP[i];
            float4 e;
            e.x = __expf(l.x - mm[i]) * iz[i];
            e.y = __expf(l.y - mm[i]) * iz[i];
            e.z = __expf(l.z - mm[i]) * iz[i];
            e.w = __expf(l.w - mm[i]) * iz[i];
            *(float4*)&attn_b[(size_t)(prow + 16 * i) * 2048 + t0 + pc4] = e;
            half4 ph;
            ph[0] = (h16)e.x; ph[1] = (h16)e.y; ph[2] = (h16)e.z; ph[3] = (h16)e.w;
            *(half4*)&Ps[(prow + 16 * i) * 72 + pc4] = ph;
        }
#pragma unroll
        for (int i = 0; i < 4; i++)
            *(half8*)&Vs[(vrow + 32 * i) * 72 + vc8] = preV[i];
        if (t0 + 64 < 2048) {
#pragma unroll
            for (int i = 0; i < 8; i++)
                preP[i] = *(const float4*)&attn_b[(size_t)(prow + 16 * i) * 2048 + t0 + 64 + pc4];
#pragma unroll
            for (int i = 0; i < 4; i++)
                preV[i] = *(const half8*)&vT_b[(vrow + 32 * i) * 2048 + t0 + 64 + vc8];
        }
        __syncthreads();
#pragma unroll
        for (int ks = 0; ks < 2; ks++) {
            half8 a[4], b[4];
#pragma unroll
            for (int f = 0; f < 4; f++) {
                a[f] = *(const half8*)&Ps[(wm + f * 16 + lrow) * 72 + ks * 32 + quad * 8];
                b[f] = *(const half8*)&Vs[(wn + f * 16 + lrow) * 72 + ks * 32 + quad * 8];
            }
            for (int mf = 0; mf < 4; mf++)
                for (int nf = 0; nf < 4; nf++)
                    acc[mf][nf] = MFMA16(a[mf], b[nf], acc[mf][nf]);
        }
        __syncthreads();
    }
    int b = bh >> 3, h = bh & 7;
    for (int nf = 0; nf < 4; nf++) {
        int d = wn + nf * 16 + lrow;
        for (int mf = 0; mf < 4; mf++)
            for (int r = 0; r < 4; r++) {
                int s = s0 + wm + mf * 16 + quad * 4 + r;
                ctx[(b * 2048 + s) * 1024 + h * 128 + d] = (h16)acc[mf][nf][r];
            }
    }
}

// -------- output GEMM: out = x + (ctx @ WoT + bo) * gamma --------
__global__ __launch_bounds__(256, 2) void gemm_out(
    const h16* __restrict__ Ah_g, const h16* __restrict__ Bh_g, const float* __restrict__ bo,
    const float* __restrict__ x, const float* __restrict__ gamma_p, float* __restrict__ out) {
    __shared__ h16 As[128 * 32];
    __shared__ h16 Bs[128 * 32];
    int tid = threadIdx.x;
    int m0 = blockIdx.y * 128, n0 = blockIdx.x * 128;
    int wid = tid >> 6, lane = tid & 63;
    int wm = (wid >> 1) * 64, wn = (wid & 1) * 64;
    int lrow = lane & 15, quad = lane >> 4;
    int srow = lane >> 2;
    int scol = (lane & 3) * 8;
    floatx4 acc[4][4] = {};
    for (int kt = 0; kt < 1024; kt += 32) {
        for (int j = 0; j < 2; j++) {
            int rb = j * 64 + wid * 16;
            int r = rb + srow;
            gload16(&Ah_g[(size_t)(m0 + r) * 1024 + kt + scol], &As[rb * 32]);
            gload16(&Bh_g[(size_t)(n0 + r) * 1024 + kt + scol], &Bs[rb * 32]);
        }
        __syncthreads();
        half8 a[4], b[4];
        for (int f = 0; f < 4; f++) {
            a[f] = *(const half8*)&As[(wm + f * 16 + lrow) * 32 + quad * 8];
            b[f] = *(const half8*)&Bs[(wn + f * 16 + lrow) * 32 + quad * 8];
        }
        for (int mf = 0; mf < 4; mf++)
            for (int nf = 0; nf < 4; nf++)
                acc[mf][nf] = MFMA16(a[mf], b[nf], acc[mf][nf]);
        __syncthreads();
    }
    float g = *gamma_p;
    for (int nf = 0; nf < 4; nf++) {
        int n = n0 + wn + nf * 16 + lrow;
        float bb = bo[n];
        for (int mf = 0; mf < 4; mf++)
            for (int r = 0; r < 4; r++) {
                int mg = m0 + wm + mf * 16 + quad * 4 + r;
                out[mg * 1024 + n] = x[mg * 1024 + n] + (acc[mf][nf][r] + bb) * g;
            }
    }
}

extern "C" void kernel_launch(void* const* d_in, const int* in_sizes, int n_in,
                              void* d_out, int out_size, void* d_ws, size_t ws_size,
                              hipStream_t stream) {
    const float* x = (const float*)d_in[0];
    const float* wq = (const float*)d_in[1];
    const float* bq = (const float*)d_in[2];
    const float* uq = (const float*)d_in[3];
    const float* wk = (const float*)d_in[4];
    const float* bk = (const float*)d_in[5];
    const float* uk = (const float*)d_in[6];
    const float* wv = (const float*)d_in[7];
    const float* bv = (const float*)d_in[8];
    const float* uv = (const float*)d_in[9];
    const float* wo = (const float*)d_in[10];
    const float* bo = (const float*)d_in[11];
    const float* uo = (const float*)d_in[12];
    const float* gamma = (const float*)d_in[13];
    float* out_f = (float*)d_out;
    float* attn = out_f + 8388608;  // [4,8,2048,2048]

    char* ws = (char*)d_ws;
    size_t o = 0;
    auto alloc = [&](size_t b) { size_t r = o; o += (b + 255) & ~(size_t)255; return r; };
    const size_t SZ_X = (size_t)8192 * 1024 * 2;   // f16 [8192][1024]
    const size_t SZ_W = (size_t)1024 * 1024 * 2;   // f16 [1024][1024]
    const size_t SZ_Q = (size_t)32 * 2048 * 128 * 2;  // f16 [bh][s][d]
    h16* xh = (h16*)(ws + alloc(SZ_X));
    h16* xl = (h16*)(ws + alloc(SZ_X));
    h16* wqhT = (h16*)(ws + alloc(SZ_W));
    h16* wqlT = (h16*)(ws + alloc(SZ_W));
    h16* wkhT = (h16*)(ws + alloc(SZ_W));
    h16* wklT = (h16*)(ws + alloc(SZ_W));
    h16* wvhT = (h16*)(ws + alloc(SZ_W));
    h16* wvlT = (h16*)(ws + alloc(SZ_W));
    h16* wohT = (h16*)(ws + alloc(SZ_W));
    h16* wolT = (h16*)(ws + alloc(SZ_W));
    h16* qh = (h16*)(ws + alloc(SZ_Q));
    h16* ql = (h16*)(ws + alloc(SZ_Q));
    h16* kh = (h16*)(ws + alloc(SZ_Q));
    h16* kl = (h16*)(ws + alloc(SZ_Q));
    h16* vh = (h16*)(ws + alloc(SZ_Q));
    h16* vT = (h16*)(ws + alloc(SZ_Q));
    h16* ctx = (h16*)(ws + alloc(SZ_Q));
    float* tvec = (float*)(ws + alloc(4096 * 4));
    float* sacc = (float*)(ws + alloc(8 * 4));
    float* isig = (float*)(ws + alloc(4 * 4));
    float* m_arr = (float*)(ws + alloc(65536 * 4));
    float* z_arr = (float*)(ws + alloc(65536 * 4));
    // stat partials overlay ctx (consumed by combine_stats before gemm_pv writes ctx)
    float* pmax = (float*)ctx;
    float* psum = pmax + (size_t)65536 * 32;

    (void)hipMemsetAsync(sacc, 0, 8 * 4, stream);
    sigma_s1<<<dim3(256, 4), 256, 0, stream>>>(wq, wk, wv, wo, uq, uk, uv, uo, tvec, sacc);
    sigma_s2<<<dim3(4, 4), 256, 0, stream>>>(wq, wk, wv, wo, tvec, sacc);
    sigma_s3<<<1, 64, 0, stream>>>(sacc, isig);

    prep_w<<<dim3(32, 32), dim3(32, 8), 0, stream>>>(wq, isig, 0, wqhT, wqlT);
    prep_w<<<dim3(32, 32), dim3(32, 8), 0, stream>>>(wk, isig, 1, wkhT, wklT);
    prep_w<<<dim3(32, 32), dim3(32, 8), 0, stream>>>(wv, isig, 2, wvhT, wvlT);
    prep_w<<<dim3(32, 32), dim3(32, 8), 0, stream>>>(wo, isig, 3, wohT, wolT);
    prep_x<<<8192, 256, 0, stream>>>((const float4*)x, (half4*)xh, (half4*)xl);

    gemm_proj<1><<<dim3(8, 64), 256, 0, stream>>>(xh, xl, wqhT, wqlT, bq, qh, ql);
    gemm_proj<1><<<dim3(8, 64), 256, 0, stream>>>(xh, xl, wkhT, wklT, bk, kh, kl);
    gemm_proj<0><<<dim3(8, 64), 256, 0, stream>>>(xh, xl, wvhT, wvlT, bv, vh, nullptr);
    transpose_v<<<dim3(64, 4, 32), dim3(32, 8), 0, stream>>>(vh, vT);

    gemm_logits<<<dim3(16, 16, 32), 256, 0, stream>>>(qh, ql, kh, kl, attn, pmax, psum);
    combine_stats<<<256, 256, 0, stream>>>(pmax, psum, m_arr, z_arr);
    gemm_pv<<<dim3(16, 32), 256, 0, stream>>>(attn, vT, m_arr, z_arr, ctx);
    gemm_out<<<dim3(8, 64), 256, 0, stream>>>(ctx, wohT, bo, x, gamma, out_f);

    (void)in_sizes; (void)n_in; (void)out_size; (void)ws_size;
}